// Round 19
// baseline (125.729 us; speedup 1.0000x reference)
//
#include <hip/hip_runtime.h>
#include <hip/hip_bf16.h>
#include <math.h>

#define B_ 4
#define N_ 4096
#define D_ 256
#define H_ 8
#define HD_ 32
#define TOKENS (B_ * N_)   // 16384
#define EPSF 1e-9f
#define KV_CH 64           // kv partial chunks

typedef __bf16 bf16x8 __attribute__((ext_vector_type(8)));
typedef float f32x4 __attribute__((ext_vector_type(4)));
typedef ushort ushort8_t __attribute__((ext_vector_type(8)));

__device__ __forceinline__ float elu1(float x) { return x > 0.f ? x + 1.f : __expf(x); }

__device__ __forceinline__ ushort f2bf(float f) {
    __hip_bfloat16 h = __float2bfloat16(f);
    return *reinterpret_cast<ushort*>(&h);
}

#define GLOAD_LDS16(g, l)                                                              \
    __builtin_amdgcn_global_load_lds((__attribute__((address_space(1))) const void*)(g), \
                                     (__attribute__((address_space(3))) void*)(l), 16, 0, 0)

#define MFMA16(a, b, c) __builtin_amdgcn_mfma_f32_16x16x32_bf16((a), (b), (c), 0, 0, 0)

// ---------------- converts: W (4 mats) and x -> bf16, one launch ----------------
__global__ __launch_bounds__(256) void k_cvt_all(const float* __restrict__ Wq,
                                                 const float* __restrict__ Wk,
                                                 const float* __restrict__ Wv,
                                                 const float* __restrict__ Wo,
                                                 const float* __restrict__ x,
                                                 ushort* __restrict__ wdst,
                                                 ushort* __restrict__ xdst) {
    const int bid = blockIdx.x;
    if (bid < 128) {
        const int i = bid * 256 + threadIdx.x;  // 32768 threads x 8 els
        const int sel = i >> 13;
        const float* src = sel == 0 ? Wq : sel == 1 ? Wk : sel == 2 ? Wv : Wo;
        const int j = i & 8191;
        const float4* s = (const float4*)src + (size_t)j * 2;
        const float4 a = s[0], b = s[1];
        ushort8_t o;
        o[0] = f2bf(a.x); o[1] = f2bf(a.y); o[2] = f2bf(a.z); o[3] = f2bf(a.w);
        o[4] = f2bf(b.x); o[5] = f2bf(b.y); o[6] = f2bf(b.z); o[7] = f2bf(b.w);
        *((ushort8_t*)wdst + i) = o;
        return;
    }
    const int i = (bid - 128) * 256 + threadIdx.x;   // 524288 chunks exactly
    const float4* s = (const float4*)x + (size_t)i * 2;
    const float4 a = s[0], b = s[1];
    ushort8_t o;
    o[0] = f2bf(a.x); o[1] = f2bf(a.y); o[2] = f2bf(a.z); o[3] = f2bf(a.w);
    o[4] = f2bf(b.x); o[5] = f2bf(b.y); o[6] = f2bf(b.z); o[7] = f2bf(b.w);
    *((ushort8_t*)xdst + i) = o;
}

// ================= qkv full-K: C[16384,768] = xb @ Wall^T, 128x128, ONE stage ========
// 768 blocks x 256 thr; As+Bs = 128 KB LDS (1 block/CU, 3 exact rounds).
// Whole K staged once -> single vmcnt drain + barrier pair per block.
// XOR swizzle (r&7)<<4 applied via inverse-swizzled gload_lds SOURCE (T21).
__global__ __launch_bounds__(256) void k_qkvFK(const ushort* __restrict__ xb,
                                               const ushort* __restrict__ wall,
                                               const float* __restrict__ bv,
                                               ushort* __restrict__ qpre,
                                               ushort* __restrict__ kb,
                                               ushort* __restrict__ vb) {
    __shared__ ushort As[128 * 256];   // 64 KB, 512 B rows, swizzled
    __shared__ ushort Bs[128 * 256];   // 64 KB
    const int t = threadIdx.x;
    const int w = t >> 6, lane = t & 63;
    const int qi = blockIdx.x;             // 0..767
    const int bx = qi & 127, by = qi >> 7;
    const int rowBase = bx * 128;
    const int eBase = by * 128;            // out-col base in [0,768)
    const int sel = eBase >> 8;            // 0=q, 1=k, 2=v
    const int colOff = eBase & 255;

    // ---- stage both panels: 8192 x 16B chunks, 32 per thread ----
#pragma unroll
    for (int j = 0; j < 16; ++j) {
        const int chunk = j * 256 + t;               // A chunks 0..4095
        const int r = chunk >> 5, c16 = chunk & 31;
        GLOAD_LDS16(xb + (size_t)(rowBase + r) * 256 + ((c16 ^ (r & 7)) << 3),
                    (char*)As + chunk * 16);
        const int chunk2 = chunk + 4096;             // B chunks
        GLOAD_LDS16(wall + (size_t)(eBase + r) * 256 + ((c16 ^ (r & 7)) << 3),
                    (char*)Bs + chunk * 16);
        (void)chunk2;
    }
    __syncthreads();   // single drain

    const int wr = w >> 1, wc = w & 1;     // 2x2 waves; wave tile 64 rows x 64 cols
    const int q_ = lane >> 4;
    f32x4 acc[4][4] = {};
#pragma unroll
    for (int it = 0; it < 8; ++it) {
        const int kt = it * 32;
        bf16x8 af[4], bfr[4];
#pragma unroll
        for (int m = 0; m < 4; ++m) {
            const int r = wr * 64 + m * 16 + (lane & 15);
            const int byte = (r * 512 + (kt + q_ * 8) * 2) ^ ((r & 7) << 4);
            af[m] = *(const bf16x8*)((const char*)As + byte);
        }
#pragma unroll
        for (int n = 0; n < 4; ++n) {
            const int e = wc * 64 + n * 16 + (lane & 15);
            const int byte = (e * 512 + (kt + q_ * 8) * 2) ^ ((e & 7) << 4);
            bfr[n] = *(const bf16x8*)((const char*)Bs + byte);
        }
#pragma unroll
        for (int m = 0; m < 4; ++m)
#pragma unroll
            for (int n = 0; n < 4; ++n)
                acc[m][n] = MFMA16(af[m], bfr[n], acc[m][n]);
    }

#pragma unroll
    for (int m = 0; m < 4; ++m)
#pragma unroll
        for (int n = 0; n < 4; ++n)
#pragma unroll
            for (int j = 0; j < 4; ++j) {
                const int row = rowBase + wr * 64 + m * 16 + (lane >> 4) * 4 + j;
                const int col = colOff + wc * 64 + n * 16 + (lane & 15);
                const size_t go = (size_t)row * 256 + col;
                const float v = acc[m][n][j];
                if (sel == 0)      qpre[go] = f2bf(v);
                else if (sel == 1) kb[go]   = f2bf(elu1(v));
                else               vb[go]   = f2bf(elu1(v + bv[col]));
            }
}

// ================= hetero THIN+THIN: bias rows + kv partials, 1:1 interleave =========
// 4096 blocks x 256 thr. Even bids: kvpart chunk; odd bids: bias 8-row block (nt).
__global__ __launch_bounds__(256, 4) void k_mixBP(const float* __restrict__ prior,
                                                  const ushort* __restrict__ kmat,
                                                  const ushort* __restrict__ vmat,
                                                  float* __restrict__ bias,
                                                  float* __restrict__ part) {
    const int t = threadIdx.x;
    const int w = t >> 6, lane = t & 63;
    const int bid = blockIdx.x;

    if (bid & 1) {
        // ---- bias block (round-7 proven): 8 rows, nt loads ----
        const int base = (bid >> 1) * 8;
#pragma unroll
        for (int rr = 0; rr < 2; ++rr) {
            const int row = base + w + rr * 4;
            const f32x4* p = (const f32x4*)(prior + (size_t)row * N_);
            float s0 = 0.f, s1 = 0.f, s2 = 0.f, s3 = 0.f;
#pragma unroll
            for (int i = 0; i < 4; ++i) {
                const f32x4 a = __builtin_nontemporal_load(p + (i * 4 + 0) * 64 + lane);
                const f32x4 b = __builtin_nontemporal_load(p + (i * 4 + 1) * 64 + lane);
                const f32x4 c = __builtin_nontemporal_load(p + (i * 4 + 2) * 64 + lane);
                const f32x4 d = __builtin_nontemporal_load(p + (i * 4 + 3) * 64 + lane);
                s0 += a[0] + a[1] + a[2] + a[3];
                s1 += b[0] + b[1] + b[2] + b[3];
                s2 += c[0] + c[1] + c[2] + c[3];
                s3 += d[0] + d[1] + d[2] + d[3];
            }
            float s = (s0 + s1) + (s2 + s3);
#pragma unroll
            for (int off = 32; off; off >>= 1) s += __shfl_xor(s, off, 64);
            if (lane == 0) bias[row] = s * (1.0f / N_);
        }
        return;
    }

    // ---- kvpart block (round-15 proven): one 64-row chunk, no atomics ----
    __shared__ float kt_[64][32];
    __shared__ float vt_[64][32];
    const int pidx = bid >> 1;            // 0..2047
    const int bh = pidx & 31, chy = pidx >> 5;
    const int b = bh >> 3, h = bh & 7;
    const int tok0 = b * N_ + chy * 64;
    const int m = t >> 3;
    const int lvec = (t & 7) * 4;
#pragma unroll
    for (int half = 0; half < 2; ++half) {
        const int rr = (t >> 3) + half * 32;
        const size_t g = (size_t)(tok0 + rr) * D_ + h * HD_ + lvec;
        const ushort4 ku = *(const ushort4*)(kmat + g);
        const ushort4 vu = *(const ushort4*)(vmat + g);
        kt_[rr][lvec + 0] = __bfloat162float(*(const __hip_bfloat16*)&ku.x);
        kt_[rr][lvec + 1] = __bfloat162float(*(const __hip_bfloat16*)&ku.y);
        kt_[rr][lvec + 2] = __bfloat162float(*(const __hip_bfloat16*)&ku.z);
        kt_[rr][lvec + 3] = __bfloat162float(*(const __hip_bfloat16*)&ku.w);
        vt_[rr][lvec + 0] = __bfloat162float(*(const __hip_bfloat16*)&vu.x);
        vt_[rr][lvec + 1] = __bfloat162float(*(const __hip_bfloat16*)&vu.y);
        vt_[rr][lvec + 2] = __bfloat162float(*(const __hip_bfloat16*)&vu.z);
        vt_[rr][lvec + 3] = __bfloat162float(*(const __hip_bfloat16*)&vu.w);
    }
    __syncthreads();
    float4 acc = {0.f, 0.f, 0.f, 0.f};
    float4 sk = {0.f, 0.f, 0.f, 0.f};
#pragma unroll 4
    for (int r = 0; r < 64; ++r) {
        const float vv = vt_[r][m];
        const float4 kk = *(const float4*)&kt_[r][lvec];
        acc.x = fmaf(vv, kk.x, acc.x);
        acc.y = fmaf(vv, kk.y, acc.y);
        acc.z = fmaf(vv, kk.z, acc.z);
        acc.w = fmaf(vv, kk.w, acc.w);
        sk.x += kk.x; sk.y += kk.y; sk.z += kk.z; sk.w += kk.w;
    }
    float* outp = part + ((size_t)chy * 32 + bh) * 1056;
    *(float4*)(outp + m * 32 + lvec) = acc;
    if (m == 0) *(float4*)(outp + 1024 + lvec) = sk;
}

// ---------------- Stage B: reduce 64 partials -> kv/ksum (overwrite) ----------------
__global__ __launch_bounds__(256) void k_kvred(const float* __restrict__ part,
                                               float* __restrict__ kv,
                                               float* __restrict__ ksum) {
    const int i = blockIdx.x * 256 + threadIdx.x;   // 0..33791
    if (i >= 32 * 1056) return;
    const int bh = i / 1056, r = i - bh * 1056;
    float s = 0.f;
#pragma unroll 8
    for (int c = 0; c < KV_CH; ++c) s += part[((size_t)c * 32 + bh) * 1056 + r];
    if (r < 1024) kv[(size_t)bh * 1024 + r] = s;
    else          ksum[(size_t)bh * 32 + (r - 1024)] = s;
}

// ================= K3: q-finalize + attn + out-GEMM =================
__global__ __launch_bounds__(512, 2) void k_fusedB(const ushort* __restrict__ qpre,
                                                   const float* __restrict__ bias_g,
                                                   const float* __restrict__ kv,
                                                   const float* __restrict__ ksum,
                                                   const ushort* __restrict__ wo,
                                                   const float* __restrict__ bo,
                                                   float* __restrict__ out) {
    __shared__ ushort qs[64 * 256];    // linear bf16 q tile (32 KB)
    __shared__ ushort at_s[64 * 256];  // swizzled bf16 attn tile (32 KB)
    __shared__ ushort Ws2[256 * 32];   // 16 KB wo slice, slot-swizzled
    const int t = threadIdx.x;
    const int w = t >> 6, lane = t & 63;
    const int tokBase = blockIdx.x * 64;
    const int b = tokBase >> 12;

#pragma unroll
    for (int j = 0; j < 4; ++j) {
        const int chunk = j * 512 + t;
        GLOAD_LDS16(qpre + (size_t)tokBase * 256 + (size_t)chunk * 8,
                    (char*)qs + chunk * 16);
    }

    const int c = t & 255;
    const int h = c >> 5, m = c & 31;
    f32x4 kvr[8], ksr[8];
#pragma unroll
    for (int i = 0; i < 8; ++i) {
        kvr[i] = *(const f32x4*)(kv + (((size_t)(b * H_ + h) * HD_ + m) * HD_) + i * 4);
        ksr[i] = *(const f32x4*)(ksum + (size_t)(b * H_ + h) * HD_ + i * 4);
    }
    __syncthreads();

    {
        const int r = t >> 3;
        const float brow = bias_g[tokBase + r];
        const int cb = (t & 7) * 32;
#pragma unroll
        for (int i = 0; i < 4; ++i) {
            bf16x8 qv = *(bf16x8*)(qs + r * 256 + cb + i * 8);
#pragma unroll
            for (int j = 0; j < 8; ++j) qv[j] = (__bf16)elu1((float)qv[j] + brow);
            *(bf16x8*)(qs + r * 256 + cb + i * 8) = qv;
        }
    }
    __syncthreads();

    for (int tok2 = 0; tok2 < 32; ++tok2) {
        const int tok = tok2 * 2 + (t >> 8);
        float num = 0.f, den = 0.f;
#pragma unroll
        for (int i = 0; i < 4; ++i) {
            const bf16x8 qv = *(const bf16x8*)(qs + tok * 256 + h * HD_ + i * 8);
#pragma unroll
            for (int j = 0; j < 8; ++j) {
                const float qf = (float)qv[j];
                num = fmaf(qf, ((const float*)kvr)[i * 8 + j], num);
                den = fmaf(qf, ((const float*)ksr)[i * 8 + j], den);
            }
        }
        const float a = num / (den + EPSF);
        const int byte = (tok * 512 + c * 2) ^ ((tok & 7) << 4);
        *(ushort*)((char*)at_s + byte) = f2bf(a);
    }

    const int wr = w >> 2, wc = w & 3;
    const int q_ = lane >> 4;
    f32x4 acc[2][4] = {};
    for (int kt = 0; kt < 256; kt += 32) {
        __syncthreads();
#pragma unroll
        for (int j = 0; j < 2; ++j) {
            const int ch = j * 512 + t;           // 0..1023
            const int e = ch >> 2;
            const int pslot = ch & 3;
            const int qsrc = pslot ^ ((e >> 1) & 3);
            GLOAD_LDS16(wo + (size_t)e * 256 + kt + qsrc * 8, (char*)Ws2 + ch * 16);
        }
        __syncthreads();
        bf16x8 af[2];
#pragma unroll
        for (int mm = 0; mm < 2; ++mm) {
            const int r = wr * 32 + mm * 16 + (lane & 15);
            const int byte = (r * 512 + (kt + q_ * 8) * 2) ^ ((r & 7) << 4);
            af[mm] = *(const bf16x8*)((const char*)at_s + byte);
        }
#pragma unroll
        for (int n = 0; n < 4; ++n) {
            const int e = wc * 64 + n * 16 + (lane & 15);
            const int wbyte = e * 64 + ((q_ ^ ((e >> 1) & 3)) * 16);
            const bf16x8 bw = *(const bf16x8*)((const char*)Ws2 + wbyte);
#pragma unroll
            for (int mm = 0; mm < 2; ++mm)
                acc[mm][n] = MFMA16(af[mm], bw, acc[mm][n]);
        }
    }
#pragma unroll
    for (int mm = 0; mm < 2; ++mm)
#pragma unroll
        for (int n = 0; n < 4; ++n)
#pragma unroll
            for (int j = 0; j < 4; ++j) {
                const int row = tokBase + wr * 32 + mm * 16 + (lane >> 4) * 4 + j;
                const int col = wc * 64 + n * 16 + (lane & 15);
                out[(size_t)row * 256 + col] = acc[mm][n][j] + bo[col];
            }
}

extern "C" void kernel_launch(void* const* d_in, const int* in_sizes, int n_in,
                              void* d_out, int out_size, void* d_ws, size_t ws_size,
                              hipStream_t stream) {
    const float* x     = (const float*)d_in[0];
    const float* prior = (const float*)d_in[1];
    const float* Wq    = (const float*)d_in[2];
    const float* Wk    = (const float*)d_in[3];
    const float* Wv    = (const float*)d_in[4];
    const float* bv    = (const float*)d_in[5];
    const float* Wo    = (const float*)d_in[6];
    const float* bo    = (const float*)d_in[7];
    float* out = (float*)d_out;

    // workspace layout (round-18 shape)
    char* w8 = (char*)d_ws;
    ushort* qpre = (ushort*)w8;                         // 8 MB bf16
    ushort* kb   = qpre + (size_t)TOKENS * D_;
    ushort* vb   = kb + (size_t)TOKENS * D_;
    ushort* xb   = vb + (size_t)TOKENS * D_;            // 8 MB bf16
    ushort* wall = xb + (size_t)TOKENS * D_;            // wq|wk|wv|wo bf16
    ushort* wob  = wall + 3 * 65536;
    float* kvb   = (float*)(wall + 4 * 65536);          // 128 KB
    float* ksb   = kvb + 32768;                         // 4 KB
    float* bias  = ksb + 1024;                          // 64 KB
    float* part  = bias + TOKENS;                       // 8.65 MB

    k_cvt_all<<<2176, 256, 0, stream>>>(Wq, Wk, Wv, Wo, x, wall, xb);

    k_qkvFK<<<768, 256, 0, stream>>>(xb, wall, bv, qpre, kb, vb);

    k_mixBP<<<4096, 256, 0, stream>>>(prior, kb, vb, bias, part);

    k_kvred<<<132, 256, 0, stream>>>(part, kvb, ksb);

    k_fusedB<<<256, 512, 0, stream>>>(qpre, bias, kvb, ksb, wob, bo, out);
}

// Round 20
// 113.472 us; speedup vs baseline: 1.1080x; 1.1080x over previous
//
#include <hip/hip_runtime.h>
#include <hip/hip_bf16.h>
#include <math.h>

#define B_ 4
#define N_ 4096
#define D_ 256
#define H_ 8
#define HD_ 32
#define TOKENS (B_ * N_)   // 16384
#define EPSF 1e-9f
#define KV_CH 64           // kv partial chunks

typedef __bf16 bf16x8 __attribute__((ext_vector_type(8)));
typedef float f32x4 __attribute__((ext_vector_type(4)));
typedef ushort ushort8_t __attribute__((ext_vector_type(8)));

__device__ __forceinline__ float elu1(float x) { return x > 0.f ? x + 1.f : __expf(x); }

__device__ __forceinline__ ushort f2bf(float f) {
    __hip_bfloat16 h = __float2bfloat16(f);
    return *reinterpret_cast<ushort*>(&h);
}

#define GLOAD_LDS16(g, l)                                                              \
    __builtin_amdgcn_global_load_lds((__attribute__((address_space(1))) const void*)(g), \
                                     (__attribute__((address_space(3))) void*)(l), 16, 0, 0)

#define MFMA16(a, b, c) __builtin_amdgcn_mfma_f32_16x16x32_bf16((a), (b), (c), 0, 0, 0)

// ---------------- all four W matrices -> bf16, concatenated ----------------
__global__ __launch_bounds__(256) void k_cvt_w(const float* __restrict__ Wq,
                                               const float* __restrict__ Wk,
                                               const float* __restrict__ Wv,
                                               const float* __restrict__ Wo,
                                               ushort* __restrict__ dst) {
    const int i = blockIdx.x * 256 + threadIdx.x;  // 32768 threads x 8 els
    const int sel = i >> 13;
    const float* src = sel == 0 ? Wq : sel == 1 ? Wk : sel == 2 ? Wv : Wo;
    const int j = i & 8191;
    const float4* s = (const float4*)src + (size_t)j * 2;
    const float4 a = s[0], b = s[1];
    ushort8_t o;
    o[0] = f2bf(a.x); o[1] = f2bf(a.y); o[2] = f2bf(a.z); o[3] = f2bf(a.w);
    o[4] = f2bf(b.x); o[5] = f2bf(b.y); o[6] = f2bf(b.z); o[7] = f2bf(b.w);
    *((ushort8_t*)dst + i) = o;
}

// ================= K1: hetero blocks, 256 thr, 32 KB LDS (4-5 blocks/CU) =============
// bid%7 < 3  (1536 blocks): ONE matrix (q|k|v) x 32-row tile; consecutive bids share x
// bid%7 >= 3 (2048 blocks): bias 8-row nt block (round-7 proven body)
__global__ __launch_bounds__(256, 4) void k_mix7(const float* __restrict__ prior,
                                                 const float* __restrict__ x,
                                                 const ushort* __restrict__ wq,
                                                 const ushort* __restrict__ wk,
                                                 const ushort* __restrict__ wv,
                                                 const float* __restrict__ bv,
                                                 float* __restrict__ bias_g,
                                                 ushort* __restrict__ qpre,
                                                 ushort* __restrict__ kb,
                                                 ushort* __restrict__ vb) {
    __shared__ ushort As[32 * 256];   // 16 KB bf16 x-tile, XOR-swizzled
    __shared__ ushort Ws[256 * 32];   // 16 KB: one matrix slice, slot-swizzled
    const int t = threadIdx.x;
    const int w = t >> 6, lane = t & 63;
    const int bid = blockIdx.x;
    const int grp = bid / 7, pos = bid % 7;

    if (pos >= 3) {
        // ---- bias block: 8 rows, wave w sums rows base+w, base+w+4 (nt loads) ----
        const int base = (grp * 4 + (pos - 3)) * 8;
#pragma unroll
        for (int rr = 0; rr < 2; ++rr) {
            const int row = base + w + rr * 4;
            const f32x4* p = (const f32x4*)(prior + (size_t)row * N_);
            float s0 = 0.f, s1 = 0.f, s2 = 0.f, s3 = 0.f;
#pragma unroll
            for (int i = 0; i < 4; ++i) {
                const f32x4 a = __builtin_nontemporal_load(p + (i * 4 + 0) * 64 + lane);
                const f32x4 b = __builtin_nontemporal_load(p + (i * 4 + 1) * 64 + lane);
                const f32x4 c = __builtin_nontemporal_load(p + (i * 4 + 2) * 64 + lane);
                const f32x4 d = __builtin_nontemporal_load(p + (i * 4 + 3) * 64 + lane);
                s0 += a[0] + a[1] + a[2] + a[3];
                s1 += b[0] + b[1] + b[2] + b[3];
                s2 += c[0] + c[1] + c[2] + c[3];
                s3 += d[0] + d[1] + d[2] + d[3];
            }
            float s = (s0 + s1) + (s2 + s3);
#pragma unroll
            for (int off = 32; off; off >>= 1) s += __shfl_xor(s, off, 64);
            if (lane == 0) bias_g[row] = s * (1.0f / N_);
        }
        return;
    }

    // ---- qkv block: tile grp (rows grp*32..+31), matrix pos (0=q,1=k,2=v) ----
    const ushort* wm = pos == 0 ? wq : pos == 1 ? wk : wv;
    const int rowBase = grp * 32;

    // stage x (fp32 -> bf16, swizzled): 32 els/thread
    {
        const int r = t >> 3;             // 0..31
        const int c0 = (t & 7) * 4;       // 0..28
#pragma unroll
        for (int j = 0; j < 8; ++j) {
            const int c = c0 + j * 32;
            const float4 xv = *(const float4*)(x + (size_t)(rowBase + r) * 256 + c);
            ushort4 o;
            o.x = f2bf(xv.x); o.y = f2bf(xv.y); o.z = f2bf(xv.z); o.w = f2bf(xv.w);
            const int byte = (r * 512 + c * 2) ^ ((r & 7) << 4);
            *(ushort4*)((char*)As + byte) = o;
        }
    }

    const int q_ = lane >> 4;             // k-quarter 0..3
    f32x4 acc[2][4] = {};

    for (int kt = 0; kt < 256; kt += 32) {
        __syncthreads();   // Ws reuse fence (covers A-stage on first iter)
#pragma unroll
        for (int j = 0; j < 4; ++j) {
            const int cc = j * 256 + t;           // 0..1023
            const int e = cc >> 2;
            const int pslot = cc & 3;
            const int qsrc = pslot ^ ((e >> 1) & 3);
            GLOAD_LDS16(wm + (size_t)e * 256 + kt + qsrc * 8, (char*)Ws + cc * 16);
        }
        __syncthreads();
        bf16x8 af[2];
#pragma unroll
        for (int m = 0; m < 2; ++m) {
            const int r = m * 16 + (lane & 15);
            const int abyte = (r * 512 + (kt + q_ * 8) * 2) ^ ((r & 7) << 4);
            af[m] = *(const bf16x8*)((const char*)As + abyte);
        }
#pragma unroll
        for (int n = 0; n < 4; ++n) {
            const int e = w * 64 + n * 16 + (lane & 15);
            const int wbyte = e * 64 + ((q_ ^ ((e >> 1) & 3)) * 16);
            const bf16x8 bw = *(const bf16x8*)((const char*)Ws + wbyte);
#pragma unroll
            for (int m = 0; m < 2; ++m)
                acc[m][n] = MFMA16(af[m], bw, acc[m][n]);
        }
    }

#pragma unroll
    for (int m = 0; m < 2; ++m)
#pragma unroll
        for (int n = 0; n < 4; ++n)
#pragma unroll
            for (int j = 0; j < 4; ++j) {
                const int rl = m * 16 + (lane >> 4) * 4 + j;
                const int col = w * 64 + n * 16 + (lane & 15);
                const size_t go = (size_t)(rowBase + rl) * 256 + col;
                const float v = acc[m][n][j];
                if (pos == 0)      qpre[go] = f2bf(v);
                else if (pos == 1) kb[go]   = f2bf(elu1(v));
                else               vb[go]   = f2bf(elu1(v + bv[col]));
            }
}

// ---------------- Stage A: partial kv/ksum per (bh, chunk) — NO atomics ----------------
__global__ __launch_bounds__(256) void k_kvpart(const ushort* __restrict__ kmat,
                                                const ushort* __restrict__ vmat,
                                                float* __restrict__ part) {
    const int bh = blockIdx.x;
    const int b = bh >> 3, h = bh & 7;
    const int tok0 = b * N_ + blockIdx.y * 64;
    __shared__ float kt_[64][32];
    __shared__ float vt_[64][32];
    const int t = threadIdx.x;
    const int m = t >> 3;
    const int lvec = (t & 7) * 4;
#pragma unroll
    for (int half = 0; half < 2; ++half) {
        const int rr = (t >> 3) + half * 32;
        const size_t g = (size_t)(tok0 + rr) * D_ + h * HD_ + lvec;
        const ushort4 ku = *(const ushort4*)(kmat + g);
        const ushort4 vu = *(const ushort4*)(vmat + g);
        kt_[rr][lvec + 0] = __bfloat162float(*(const __hip_bfloat16*)&ku.x);
        kt_[rr][lvec + 1] = __bfloat162float(*(const __hip_bfloat16*)&ku.y);
        kt_[rr][lvec + 2] = __bfloat162float(*(const __hip_bfloat16*)&ku.z);
        kt_[rr][lvec + 3] = __bfloat162float(*(const __hip_bfloat16*)&ku.w);
        vt_[rr][lvec + 0] = __bfloat162float(*(const __hip_bfloat16*)&vu.x);
        vt_[rr][lvec + 1] = __bfloat162float(*(const __hip_bfloat16*)&vu.y);
        vt_[rr][lvec + 2] = __bfloat162float(*(const __hip_bfloat16*)&vu.z);
        vt_[rr][lvec + 3] = __bfloat162float(*(const __hip_bfloat16*)&vu.w);
    }
    __syncthreads();
    float4 acc = {0.f, 0.f, 0.f, 0.f};
    float4 sk = {0.f, 0.f, 0.f, 0.f};
#pragma unroll 4
    for (int r = 0; r < 64; ++r) {
        const float vv = vt_[r][m];
        const float4 kk = *(const float4*)&kt_[r][lvec];
        acc.x = fmaf(vv, kk.x, acc.x);
        acc.y = fmaf(vv, kk.y, acc.y);
        acc.z = fmaf(vv, kk.z, acc.z);
        acc.w = fmaf(vv, kk.w, acc.w);
        sk.x += kk.x; sk.y += kk.y; sk.z += kk.z; sk.w += kk.w;
    }
    float* outp = part + ((size_t)blockIdx.y * 32 + bh) * 1056;
    *(float4*)(outp + m * 32 + lvec) = acc;
    if (m == 0) *(float4*)(outp + 1024 + lvec) = sk;
}

// ---------------- Stage B: reduce 64 partials -> kv/ksum (overwrite) ----------------
__global__ __launch_bounds__(256) void k_kvred(const float* __restrict__ part,
                                               float* __restrict__ kv,
                                               float* __restrict__ ksum) {
    const int i = blockIdx.x * 256 + threadIdx.x;   // 0..33791
    if (i >= 32 * 1056) return;
    const int bh = i / 1056, r = i - bh * 1056;
    float s = 0.f;
#pragma unroll 8
    for (int c = 0; c < KV_CH; ++c) s += part[((size_t)c * 32 + bh) * 1056 + r];
    if (r < 1024) kv[(size_t)bh * 1024 + r] = s;
    else          ksum[(size_t)bh * 32 + (r - 1024)] = s;
}

// ================= K3: q-finalize + attn + out-GEMM =================
__global__ __launch_bounds__(512, 2) void k_fusedB(const ushort* __restrict__ qpre,
                                                   const float* __restrict__ bias_g,
                                                   const float* __restrict__ kv,
                                                   const float* __restrict__ ksum,
                                                   const ushort* __restrict__ wo,
                                                   const float* __restrict__ bo,
                                                   float* __restrict__ out) {
    __shared__ ushort qs[64 * 256];    // linear bf16 q tile (32 KB)
    __shared__ ushort at_s[64 * 256];  // swizzled bf16 attn tile (32 KB)
    __shared__ ushort Ws2[256 * 32];   // 16 KB wo slice, slot-swizzled
    const int t = threadIdx.x;
    const int w = t >> 6, lane = t & 63;
    const int tokBase = blockIdx.x * 64;
    const int b = tokBase >> 12;

#pragma unroll
    for (int j = 0; j < 4; ++j) {
        const int chunk = j * 512 + t;
        GLOAD_LDS16(qpre + (size_t)tokBase * 256 + (size_t)chunk * 8,
                    (char*)qs + chunk * 16);
    }

    const int c = t & 255;
    const int h = c >> 5, m = c & 31;
    f32x4 kvr[8], ksr[8];
#pragma unroll
    for (int i = 0; i < 8; ++i) {
        kvr[i] = *(const f32x4*)(kv + (((size_t)(b * H_ + h) * HD_ + m) * HD_) + i * 4);
        ksr[i] = *(const f32x4*)(ksum + (size_t)(b * H_ + h) * HD_ + i * 4);
    }
    __syncthreads();

    {
        const int r = t >> 3;
        const float brow = bias_g[tokBase + r];
        const int cb = (t & 7) * 32;
#pragma unroll
        for (int i = 0; i < 4; ++i) {
            bf16x8 qv = *(bf16x8*)(qs + r * 256 + cb + i * 8);
#pragma unroll
            for (int j = 0; j < 8; ++j) qv[j] = (__bf16)elu1((float)qv[j] + brow);
            *(bf16x8*)(qs + r * 256 + cb + i * 8) = qv;
        }
    }
    __syncthreads();

    for (int tok2 = 0; tok2 < 32; ++tok2) {
        const int tok = tok2 * 2 + (t >> 8);
        float num = 0.f, den = 0.f;
#pragma unroll
        for (int i = 0; i < 4; ++i) {
            const bf16x8 qv = *(const bf16x8*)(qs + tok * 256 + h * HD_ + i * 8);
#pragma unroll
            for (int j = 0; j < 8; ++j) {
                const float qf = (float)qv[j];
                num = fmaf(qf, ((const float*)kvr)[i * 8 + j], num);
                den = fmaf(qf, ((const float*)ksr)[i * 8 + j], den);
            }
        }
        const float a = num / (den + EPSF);
        const int byte = (tok * 512 + c * 2) ^ ((tok & 7) << 4);
        *(ushort*)((char*)at_s + byte) = f2bf(a);
    }

    const int wr = w >> 2, wc = w & 3;
    const int q_ = lane >> 4;
    f32x4 acc[2][4] = {};
    for (int kt = 0; kt < 256; kt += 32) {
        __syncthreads();
#pragma unroll
        for (int j = 0; j < 2; ++j) {
            const int ch = j * 512 + t;           // 0..1023
            const int e = ch >> 2;
            const int pslot = ch & 3;
            const int qsrc = pslot ^ ((e >> 1) & 3);
            GLOAD_LDS16(wo + (size_t)e * 256 + kt + qsrc * 8, (char*)Ws2 + ch * 16);
        }
        __syncthreads();
        bf16x8 af[2];
#pragma unroll
        for (int mm = 0; mm < 2; ++mm) {
            const int r = wr * 32 + mm * 16 + (lane & 15);
            const int byte = (r * 512 + (kt + q_ * 8) * 2) ^ ((r & 7) << 4);
            af[mm] = *(const bf16x8*)((const char*)at_s + byte);
        }
#pragma unroll
        for (int n = 0; n < 4; ++n) {
            const int e = wc * 64 + n * 16 + (lane & 15);
            const int wbyte = e * 64 + ((q_ ^ ((e >> 1) & 3)) * 16);
            const bf16x8 bw = *(const bf16x8*)((const char*)Ws2 + wbyte);
#pragma unroll
            for (int mm = 0; mm < 2; ++mm)
                acc[mm][n] = MFMA16(af[mm], bw, acc[mm][n]);
        }
    }
#pragma unroll
    for (int mm = 0; mm < 2; ++mm)
#pragma unroll
        for (int n = 0; n < 4; ++n)
#pragma unroll
            for (int j = 0; j < 4; ++j) {
                const int row = tokBase + wr * 32 + mm * 16 + (lane >> 4) * 4 + j;
                const int col = wc * 64 + n * 16 + (lane & 15);
                out[(size_t)row * 256 + col] = acc[mm][n][j] + bo[col];
            }
}

extern "C" void kernel_launch(void* const* d_in, const int* in_sizes, int n_in,
                              void* d_out, int out_size, void* d_ws, size_t ws_size,
                              hipStream_t stream) {
    const float* x     = (const float*)d_in[0];
    const float* prior = (const float*)d_in[1];
    const float* Wq    = (const float*)d_in[2];
    const float* Wk    = (const float*)d_in[3];
    const float* Wv    = (const float*)d_in[4];
    const float* bv    = (const float*)d_in[5];
    const float* Wo    = (const float*)d_in[6];
    const float* bo    = (const float*)d_in[7];
    float* out = (float*)d_out;

    // workspace layout (round-15 verbatim)
    char* w8 = (char*)d_ws;
    ushort* qpre = (ushort*)w8;                         // 8 MB bf16
    ushort* kb   = qpre + (size_t)TOKENS * D_;
    ushort* vb   = kb + (size_t)TOKENS * D_;
    ushort* wqb  = vb + (size_t)TOKENS * D_;            // 4 x 128 KB bf16
    ushort* wkb  = wqb + 65536;
    ushort* wvb  = wkb + 65536;
    ushort* wob  = wvb + 65536;
    float* kvb   = (float*)(wqb + 4 * 65536);           // 128 KB
    float* ksb   = kvb + 32768;                         // 4 KB
    float* bias  = ksb + 1024;                          // 64 KB
    float* part  = bias + TOKENS;                       // 8.65 MB

    k_cvt_w<<<128, 256, 0, stream>>>(Wq, Wk, Wv, Wo, wqb);

    k_mix7<<<3584, 256, 0, stream>>>(prior, x, wqb, wkb, wvb, bv, bias, qpre, kb, vb);

    k_kvpart<<<dim3(32, KV_CH), 256, 0, stream>>>(kb, vb, part);
    k_kvred<<<132, 256, 0, stream>>>(part, kvb, ksb);

    k_fusedB<<<256, 512, 0, stream>>>(qpre, bias, kvb, ksb, wob, bo, out);
}

// Round 21
// 96.293 us; speedup vs baseline: 1.3057x; 1.1784x over previous
//
#include <hip/hip_runtime.h>
#include <hip/hip_bf16.h>
#include <math.h>

#define B_ 4
#define N_ 4096
#define D_ 256
#define H_ 8
#define HD_ 32
#define TOKENS (B_ * N_)   // 16384
#define EPSF 1e-9f

typedef __bf16 bf16x8 __attribute__((ext_vector_type(8)));
typedef float f32x4 __attribute__((ext_vector_type(4)));
typedef ushort ushort8_t __attribute__((ext_vector_type(8)));

__device__ __forceinline__ float elu1(float x) { return x > 0.f ? x + 1.f : __expf(x); }

__device__ __forceinline__ ushort f2bf(float f) {
    __hip_bfloat16 h = __float2bfloat16(f);
    return *reinterpret_cast<ushort*>(&h);
}

#define GLOAD_LDS16(g, l)                                                              \
    __builtin_amdgcn_global_load_lds((__attribute__((address_space(1))) const void*)(g), \
                                     (__attribute__((address_space(3))) void*)(l), 16, 0, 0)

#define MFMA16(a, b, c) __builtin_amdgcn_mfma_f32_16x16x32_bf16((a), (b), (c), 0, 0, 0)

// ---------------- all four W matrices -> bf16, concatenated ----------------
__global__ __launch_bounds__(256) void k_cvt_w(const float* __restrict__ Wq,
                                               const float* __restrict__ Wk,
                                               const float* __restrict__ Wv,
                                               const float* __restrict__ Wo,
                                               ushort* __restrict__ dst) {
    const int i = blockIdx.x * 256 + threadIdx.x;  // 32768 threads x 8 els
    const int sel = i >> 13;
    const float* src = sel == 0 ? Wq : sel == 1 ? Wk : sel == 2 ? Wv : Wo;
    const int j = i & 8191;
    const float4* s = (const float4*)src + (size_t)j * 2;
    const float4 a = s[0], b = s[1];
    ushort8_t o;
    o[0] = f2bf(a.x); o[1] = f2bf(a.y); o[2] = f2bf(a.z); o[3] = f2bf(a.w);
    o[4] = f2bf(b.x); o[5] = f2bf(b.y); o[6] = f2bf(b.z); o[7] = f2bf(b.w);
    *((ushort8_t*)dst + i) = o;
}

// ================= K1: hetero (round-10 proven) + fused kv-partials ==================
// bid % 5 == 0 (512 blocks): qkv GEMM tile (32 rows); k,v stay on-chip; block emits
//                            qpre + an 8448-float kv/ksum partial (per-head MFMA).
// else        (2048 blocks): bias rows — 8 rows/block, 1 row/wave, nt loads.
__global__ __launch_bounds__(512, 2) void k_mix2(const float* __restrict__ prior,
                                                 const float* __restrict__ x,
                                                 const ushort* __restrict__ wq,
                                                 const ushort* __restrict__ wk,
                                                 const ushort* __restrict__ wv,
                                                 const float* __restrict__ bv,
                                                 float* __restrict__ bias_g,
                                                 ushort* __restrict__ qpre,
                                                 float* __restrict__ part) {
    __shared__ ushort As[32 * 256];       // 16 KB bf16 x-tile, XOR-swizzled
    __shared__ ushort Ws[3 * 256 * 32];   // 48 KB W slices; reused as VT/KT tiles later
    const int t = threadIdx.x;
    const int w = t >> 6, lane = t & 63;
    const int bid = blockIdx.x;

    if (bid % 5 != 0) {
        // ---- bias block: wave w sums row bidx*8+w (16 KB) with nt loads ----
        const int bidx = bid - bid / 5 - 1;           // 0..2047
        const int row = bidx * 8 + w;
        const f32x4* p = (const f32x4*)(prior + (size_t)row * N_);
        float s0 = 0.f, s1 = 0.f, s2 = 0.f, s3 = 0.f;
#pragma unroll
        for (int i = 0; i < 4; ++i) {
            const f32x4 a = __builtin_nontemporal_load(p + (i * 4 + 0) * 64 + lane);
            const f32x4 b = __builtin_nontemporal_load(p + (i * 4 + 1) * 64 + lane);
            const f32x4 c = __builtin_nontemporal_load(p + (i * 4 + 2) * 64 + lane);
            const f32x4 d = __builtin_nontemporal_load(p + (i * 4 + 3) * 64 + lane);
            s0 += a[0] + a[1] + a[2] + a[3];
            s1 += b[0] + b[1] + b[2] + b[3];
            s2 += c[0] + c[1] + c[2] + c[3];
            s3 += d[0] + d[1] + d[2] + d[3];
        }
        float s = (s0 + s1) + (s2 + s3);
#pragma unroll
        for (int off = 32; off; off >>= 1) s += __shfl_xor(s, off, 64);
        if (lane == 0) bias_g[row] = s * (1.0f / N_);
        return;
    }

    // ---- qkv GEMM tile (round-10 proven body) ----
    const int qidx = bid / 5;             // 0..511 (chunk index; batch = qidx>>7)
    const int rowBase = qidx * 32;

    {
        const int r = t >> 4;             // 0..31
        const int c0 = (t & 15) * 4;      // 0..60
#pragma unroll
        for (int j = 0; j < 4; ++j) {
            const int c = c0 + j * 64;
            const float4 xv = *(const float4*)(x + (size_t)(rowBase + r) * 256 + c);
            ushort4 o;
            o.x = f2bf(xv.x); o.y = f2bf(xv.y); o.z = f2bf(xv.z); o.w = f2bf(xv.w);
            const int byte = (r * 512 + c * 2) ^ ((r & 7) << 4);
            *(ushort4*)((char*)As + byte) = o;
        }
    }

    const int wr = w >> 2, wc = w & 3;    // 2 x 4 waves; wave tile 16 rows x 64 cols
    const int q_ = lane >> 4;             // k-quarter 0..3
    f32x4 accq[4] = {}, acck[4] = {}, accv[4] = {};

    for (int kt = 0; kt < 256; kt += 32) {
        __syncthreads();   // also covers the A-stage on first iteration
#pragma unroll
        for (int j = 0; j < 6; ++j) {
            const int c = j * 512 + t;            // 0..3071
            const int idx = c & 1023;
            const int e = idx >> 2;
            const int pslot = idx & 3;
            const int qsrc = pslot ^ ((e >> 1) & 3);
            const ushort* srcm = (j < 2) ? wq : (j < 4) ? wk : wv;
            GLOAD_LDS16(srcm + (size_t)e * 256 + kt + qsrc * 8, (char*)Ws + c * 16);
        }
        __syncthreads();
        const int r = wr * 16 + (lane & 15);
        const int abyte = (r * 512 + (kt + q_ * 8) * 2) ^ ((r & 7) << 4);
        const bf16x8 af = *(const bf16x8*)((const char*)As + abyte);
#pragma unroll
        for (int n = 0; n < 4; ++n) {
            const int e = wc * 64 + n * 16 + (lane & 15);
            const int wbyte = e * 64 + ((q_ ^ ((e >> 1) & 3)) * 16);
            const bf16x8 bq = *(const bf16x8*)((const char*)Ws + wbyte);
            const bf16x8 bk = *(const bf16x8*)((const char*)Ws + 16384 + wbyte);
            const bf16x8 bw = *(const bf16x8*)((const char*)Ws + 32768 + wbyte);
            accq[n] = MFMA16(af, bq, accq[n]);
            acck[n] = MFMA16(af, bk, acck[n]);
            accv[n] = MFMA16(af, bw, accv[n]);
        }
    }

    __syncthreads();   // all waves done reading Ws before overlaying VT/KT

    // ---- epilogue: qpre to global; k,v (activated, bf16) into LDS tiles ----
    // VT[head][m][t] (16 KB) at Ws[0]; KT[head][d][t] (16 KB) at Ws+8192 ushorts.
    ushort* VT = Ws;
    ushort* KT = Ws + 8192;
#pragma unroll
    for (int n = 0; n < 4; ++n)
#pragma unroll
        for (int j = 0; j < 4; ++j) {
            const int rl = wr * 16 + (lane >> 4) * 4 + j;    // token t in tile
            const int col = wc * 64 + n * 16 + (lane & 15);  // 0..255
            const size_t go = (size_t)(rowBase + rl) * 256 + col;
            qpre[go] = f2bf(accq[n][j]);
            const int head = col >> 5, dm = col & 31;
            KT[head * 1024 + dm * 32 + rl] = f2bf(elu1(acck[n][j]));
            VT[head * 1024 + dm * 32 + rl] = f2bf(elu1(accv[n][j] + bv[col]));
        }
    __syncthreads();

    // ---- kv partial via MFMA: wave w = head w ----
    // kvp[m][d] = sum_t V[t][m]*K[t][d]  -> A=VT[m][t], B=KT[d][t], K=32 (one call)
    const ushort* vtw = VT + w * 1024;
    const ushort* ktw = KT + w * 1024;
    bf16x8 av[2], bk2[2];
#pragma unroll
    for (int i = 0; i < 2; ++i) {
        av[i]  = *(const bf16x8*)(vtw + (i * 16 + (lane & 15)) * 32 + (lane >> 4) * 8);
        bk2[i] = *(const bf16x8*)(ktw + (i * 16 + (lane & 15)) * 32 + (lane >> 4) * 8);
    }
    bf16x8 ones;
#pragma unroll
    for (int i = 0; i < 8; ++i) ones[i] = (__bf16)1.0f;
    f32x4 kvacc[2][2] = {};
    f32x4 ks[2] = {};
#pragma unroll
    for (int mi = 0; mi < 2; ++mi)
#pragma unroll
        for (int di = 0; di < 2; ++di)
            kvacc[mi][di] = MFMA16(av[mi], bk2[di], kvacc[mi][di]);
#pragma unroll
    for (int di = 0; di < 2; ++di) ks[di] = MFMA16(ones, bk2[di], ks[di]);

    float* pp = part + (size_t)qidx * 8448 + w * 1056;
#pragma unroll
    for (int mi = 0; mi < 2; ++mi)
#pragma unroll
        for (int di = 0; di < 2; ++di)
#pragma unroll
            for (int j = 0; j < 4; ++j) {
                const int m = mi * 16 + (lane >> 4) * 4 + j;
                const int d = di * 16 + (lane & 15);
                pp[m * 32 + d] = kvacc[mi][di][j];
            }
    if ((lane >> 4) == 0) {
        pp[1024 + (lane & 15)] = ks[0][0];
        pp[1024 + 16 + (lane & 15)] = ks[1][0];
    }
}

// ---------------- reduce 128 chunk-partials per (b,h) -> kv/ksum (overwrite) --------
__global__ __launch_bounds__(256) void k_kvred(const float* __restrict__ part,
                                               float* __restrict__ kv,
                                               float* __restrict__ ksum) {
    const int i = blockIdx.x * 256 + threadIdx.x;   // 0..33791 exactly (132*256)
    if (i >= 32 * 1056) return;
    const int bh = i / 1056, r = i - bh * 1056;
    const int b = bh >> 3, h = bh & 7;
    float s = 0.f;
#pragma unroll 8
    for (int c = 0; c < 128; ++c)
        s += part[(size_t)(b * 128 + c) * 8448 + h * 1056 + r];
    if (r < 1024) kv[(size_t)bh * 1024 + r] = s;
    else          ksum[(size_t)bh * 32 + (r - 1024)] = s;
}

// ================= K3: q-finalize + attn + out-GEMM =================
__global__ __launch_bounds__(512, 2) void k_fusedB(const ushort* __restrict__ qpre,
                                                   const float* __restrict__ bias_g,
                                                   const float* __restrict__ kv,
                                                   const float* __restrict__ ksum,
                                                   const ushort* __restrict__ wo,
                                                   const float* __restrict__ bo,
                                                   float* __restrict__ out) {
    __shared__ ushort qs[64 * 256];    // linear bf16 q tile (32 KB)
    __shared__ ushort at_s[64 * 256];  // swizzled bf16 attn tile (32 KB)
    __shared__ ushort Ws2[256 * 32];   // 16 KB wo slice, slot-swizzled
    const int t = threadIdx.x;
    const int w = t >> 6, lane = t & 63;
    const int tokBase = blockIdx.x * 64;
    const int b = tokBase >> 12;

#pragma unroll
    for (int j = 0; j < 4; ++j) {
        const int chunk = j * 512 + t;
        GLOAD_LDS16(qpre + (size_t)tokBase * 256 + (size_t)chunk * 8,
                    (char*)qs + chunk * 16);
    }

    const int c = t & 255;
    const int h = c >> 5, m = c & 31;
    f32x4 kvr[8], ksr[8];
#pragma unroll
    for (int i = 0; i < 8; ++i) {
        kvr[i] = *(const f32x4*)(kv + (((size_t)(b * H_ + h) * HD_ + m) * HD_) + i * 4);
        ksr[i] = *(const f32x4*)(ksum + (size_t)(b * H_ + h) * HD_ + i * 4);
    }
    __syncthreads();

    {
        const int r = t >> 3;
        const float brow = bias_g[tokBase + r];
        const int cb = (t & 7) * 32;
#pragma unroll
        for (int i = 0; i < 4; ++i) {
            bf16x8 qv = *(bf16x8*)(qs + r * 256 + cb + i * 8);
#pragma unroll
            for (int j = 0; j < 8; ++j) qv[j] = (__bf16)elu1((float)qv[j] + brow);
            *(bf16x8*)(qs + r * 256 + cb + i * 8) = qv;
        }
    }
    __syncthreads();

    for (int tok2 = 0; tok2 < 32; ++tok2) {
        const int tok = tok2 * 2 + (t >> 8);
        float num = 0.f, den = 0.f;
#pragma unroll
        for (int i = 0; i < 4; ++i) {
            const bf16x8 qv = *(const bf16x8*)(qs + tok * 256 + h * HD_ + i * 8);
#pragma unroll
            for (int j = 0; j < 8; ++j) {
                const float qf = (float)qv[j];
                num = fmaf(qf, ((const float*)kvr)[i * 8 + j], num);
                den = fmaf(qf, ((const float*)ksr)[i * 8 + j], den);
            }
        }
        const float a = num / (den + EPSF);
        const int byte = (tok * 512 + c * 2) ^ ((tok & 7) << 4);
        *(ushort*)((char*)at_s + byte) = f2bf(a);
    }

    const int wr = w >> 2, wc = w & 3;
    const int q_ = lane >> 4;
    f32x4 acc[2][4] = {};
    for (int kt = 0; kt < 256; kt += 32) {
        __syncthreads();
#pragma unroll
        for (int j = 0; j < 2; ++j) {
            const int ch = j * 512 + t;           // 0..1023
            const int e = ch >> 2;
            const int pslot = ch & 3;
            const int qsrc = pslot ^ ((e >> 1) & 3);
            GLOAD_LDS16(wo + (size_t)e * 256 + kt + qsrc * 8, (char*)Ws2 + ch * 16);
        }
        __syncthreads();
        bf16x8 af[2];
#pragma unroll
        for (int mm = 0; mm < 2; ++mm) {
            const int r = wr * 32 + mm * 16 + (lane & 15);
            const int byte = (r * 512 + (kt + q_ * 8) * 2) ^ ((r & 7) << 4);
            af[mm] = *(const bf16x8*)((const char*)at_s + byte);
        }
#pragma unroll
        for (int n = 0; n < 4; ++n) {
            const int e = wc * 64 + n * 16 + (lane & 15);
            const int wbyte = e * 64 + ((q_ ^ ((e >> 1) & 3)) * 16);
            const bf16x8 bw = *(const bf16x8*)((const char*)Ws2 + wbyte);
#pragma unroll
            for (int mm = 0; mm < 2; ++mm)
                acc[mm][n] = MFMA16(af[mm], bw, acc[mm][n]);
        }
    }
#pragma unroll
    for (int mm = 0; mm < 2; ++mm)
#pragma unroll
        for (int n = 0; n < 4; ++n)
#pragma unroll
            for (int j = 0; j < 4; ++j) {
                const int row = tokBase + wr * 32 + mm * 16 + (lane >> 4) * 4 + j;
                const int col = wc * 64 + n * 16 + (lane & 15);
                out[(size_t)row * 256 + col] = acc[mm][n][j] + bo[col];
            }
}

extern "C" void kernel_launch(void* const* d_in, const int* in_sizes, int n_in,
                              void* d_out, int out_size, void* d_ws, size_t ws_size,
                              hipStream_t stream) {
    const float* x     = (const float*)d_in[0];
    const float* prior = (const float*)d_in[1];
    const float* Wq    = (const float*)d_in[2];
    const float* Wk    = (const float*)d_in[3];
    const float* Wv    = (const float*)d_in[4];
    const float* bv    = (const float*)d_in[5];
    const float* Wo    = (const float*)d_in[6];
    const float* bo    = (const float*)d_in[7];
    float* out = (float*)d_out;

    // workspace layout
    char* w8 = (char*)d_ws;
    ushort* qpre = (ushort*)w8;                         // 8 MB bf16
    ushort* wqb  = qpre + (size_t)TOKENS * D_;          // 4 x 128 KB bf16
    ushort* wkb  = wqb + 65536;
    ushort* wvb  = wkb + 65536;
    ushort* wob  = wvb + 65536;
    float* kvb   = (float*)(wqb + 4 * 65536);           // 128 KB
    float* ksb   = kvb + 32768;                         // 4 KB
    float* bias  = ksb + 1024;                          // 64 KB
    float* part  = bias + TOKENS;                       // 512*8448*4 = 17.3 MB

    k_cvt_w<<<128, 256, 0, stream>>>(Wq, Wk, Wv, Wo, wqb);

    k_mix2<<<2560, 512, 0, stream>>>(prior, x, wqb, wkb, wvb, bv, bias, qpre, part);

    k_kvred<<<132, 256, 0, stream>>>(part, kvb, ksb);

    k_fusedB<<<256, 512, 0, stream>>>(qpre, bias, kvb, ksb, wob, bo, out);
}

// Round 22
// 88.160 us; speedup vs baseline: 1.4261x; 1.0923x over previous
//
#include <hip/hip_runtime.h>
#include <hip/hip_bf16.h>
#include <math.h>

#define B_ 4
#define N_ 4096
#define D_ 256
#define H_ 8
#define HD_ 32
#define TOKENS (B_ * N_)   // 16384
#define EPSF 1e-9f

typedef __bf16 bf16x8 __attribute__((ext_vector_type(8)));
typedef float f32x4 __attribute__((ext_vector_type(4)));
typedef ushort ushort8_t __attribute__((ext_vector_type(8)));

__device__ __forceinline__ float elu1(float x) { return x > 0.f ? x + 1.f : __expf(x); }

__device__ __forceinline__ ushort f2bf(float f) {
    __hip_bfloat16 h = __float2bfloat16(f);
    return *reinterpret_cast<ushort*>(&h);
}

#define GLOAD_LDS16(g, l)                                                              \
    __builtin_amdgcn_global_load_lds((__attribute__((address_space(1))) const void*)(g), \
                                     (__attribute__((address_space(3))) void*)(l), 16, 0, 0)

#define MFMA16(a, b, c) __builtin_amdgcn_mfma_f32_16x16x32_bf16((a), (b), (c), 0, 0, 0)

// ---------------- all four W matrices -> bf16, concatenated ----------------
__global__ __launch_bounds__(256) void k_cvt_w(const float* __restrict__ Wq,
                                               const float* __restrict__ Wk,
                                               const float* __restrict__ Wv,
                                               const float* __restrict__ Wo,
                                               ushort* __restrict__ dst) {
    const int i = blockIdx.x * 256 + threadIdx.x;  // 32768 threads x 8 els
    const int sel = i >> 13;
    const float* src = sel == 0 ? Wq : sel == 1 ? Wk : sel == 2 ? Wv : Wo;
    const int j = i & 8191;
    const float4* s = (const float4*)src + (size_t)j * 2;
    const float4 a = s[0], b = s[1];
    ushort8_t o;
    o[0] = f2bf(a.x); o[1] = f2bf(a.y); o[2] = f2bf(a.z); o[3] = f2bf(a.w);
    o[4] = f2bf(b.x); o[5] = f2bf(b.y); o[6] = f2bf(b.z); o[7] = f2bf(b.w);
    *((ushort8_t*)dst + i) = o;
}

// ================= K1: hetero (round-10 proven) + fused kv-partials ==================
__global__ __launch_bounds__(512, 2) void k_mix2(const float* __restrict__ prior,
                                                 const float* __restrict__ x,
                                                 const ushort* __restrict__ wq,
                                                 const ushort* __restrict__ wk,
                                                 const ushort* __restrict__ wv,
                                                 const float* __restrict__ bv,
                                                 float* __restrict__ bias_g,
                                                 ushort* __restrict__ qpre,
                                                 float* __restrict__ part) {
    __shared__ ushort As[32 * 256];       // 16 KB bf16 x-tile, XOR-swizzled
    __shared__ ushort Ws[3 * 256 * 32];   // 48 KB W slices; reused as VT/KT tiles later
    const int t = threadIdx.x;
    const int w = t >> 6, lane = t & 63;
    const int bid = blockIdx.x;

    if (bid % 5 != 0) {
        // ---- bias block: wave w sums row bidx*8+w (16 KB) with nt loads ----
        const int bidx = bid - bid / 5 - 1;           // 0..2047
        const int row = bidx * 8 + w;
        const f32x4* p = (const f32x4*)(prior + (size_t)row * N_);
        float s0 = 0.f, s1 = 0.f, s2 = 0.f, s3 = 0.f;
#pragma unroll
        for (int i = 0; i < 4; ++i) {
            const f32x4 a = __builtin_nontemporal_load(p + (i * 4 + 0) * 64 + lane);
            const f32x4 b = __builtin_nontemporal_load(p + (i * 4 + 1) * 64 + lane);
            const f32x4 c = __builtin_nontemporal_load(p + (i * 4 + 2) * 64 + lane);
            const f32x4 d = __builtin_nontemporal_load(p + (i * 4 + 3) * 64 + lane);
            s0 += a[0] + a[1] + a[2] + a[3];
            s1 += b[0] + b[1] + b[2] + b[3];
            s2 += c[0] + c[1] + c[2] + c[3];
            s3 += d[0] + d[1] + d[2] + d[3];
        }
        float s = (s0 + s1) + (s2 + s3);
#pragma unroll
        for (int off = 32; off; off >>= 1) s += __shfl_xor(s, off, 64);
        if (lane == 0) bias_g[row] = s * (1.0f / N_);
        return;
    }

    // ---- qkv GEMM tile (round-10 proven body) ----
    const int qidx = bid / 5;             // 0..511
    const int rowBase = qidx * 32;

    {
        const int r = t >> 4;             // 0..31
        const int c0 = (t & 15) * 4;      // 0..60
#pragma unroll
        for (int j = 0; j < 4; ++j) {
            const int c = c0 + j * 64;
            const float4 xv = *(const float4*)(x + (size_t)(rowBase + r) * 256 + c);
            ushort4 o;
            o.x = f2bf(xv.x); o.y = f2bf(xv.y); o.z = f2bf(xv.z); o.w = f2bf(xv.w);
            const int byte = (r * 512 + c * 2) ^ ((r & 7) << 4);
            *(ushort4*)((char*)As + byte) = o;
        }
    }

    const int wr = w >> 2, wc = w & 3;    // 2 x 4 waves; wave tile 16 rows x 64 cols
    const int q_ = lane >> 4;             // k-quarter 0..3
    f32x4 accq[4] = {}, acck[4] = {}, accv[4] = {};

    for (int kt = 0; kt < 256; kt += 32) {
        __syncthreads();   // also covers the A-stage on first iteration
#pragma unroll
        for (int j = 0; j < 6; ++j) {
            const int c = j * 512 + t;            // 0..3071
            const int idx = c & 1023;
            const int e = idx >> 2;
            const int pslot = idx & 3;
            const int qsrc = pslot ^ ((e >> 1) & 3);
            const ushort* srcm = (j < 2) ? wq : (j < 4) ? wk : wv;
            GLOAD_LDS16(srcm + (size_t)e * 256 + kt + qsrc * 8, (char*)Ws + c * 16);
        }
        __syncthreads();
        const int r = wr * 16 + (lane & 15);
        const int abyte = (r * 512 + (kt + q_ * 8) * 2) ^ ((r & 7) << 4);
        const bf16x8 af = *(const bf16x8*)((const char*)As + abyte);
#pragma unroll
        for (int n = 0; n < 4; ++n) {
            const int e = wc * 64 + n * 16 + (lane & 15);
            const int wbyte = e * 64 + ((q_ ^ ((e >> 1) & 3)) * 16);
            const bf16x8 bq = *(const bf16x8*)((const char*)Ws + wbyte);
            const bf16x8 bk = *(const bf16x8*)((const char*)Ws + 16384 + wbyte);
            const bf16x8 bw = *(const bf16x8*)((const char*)Ws + 32768 + wbyte);
            accq[n] = MFMA16(af, bq, accq[n]);
            acck[n] = MFMA16(af, bk, acck[n]);
            accv[n] = MFMA16(af, bw, accv[n]);
        }
    }

    __syncthreads();   // all waves done reading Ws before overlaying VT/KT

    // ---- epilogue: qpre to global; k,v (activated, bf16) into LDS tiles ----
    ushort* VT = Ws;
    ushort* KT = Ws + 8192;
#pragma unroll
    for (int n = 0; n < 4; ++n)
#pragma unroll
        for (int j = 0; j < 4; ++j) {
            const int rl = wr * 16 + (lane >> 4) * 4 + j;    // token t in tile
            const int col = wc * 64 + n * 16 + (lane & 15);  // 0..255
            const size_t go = (size_t)(rowBase + rl) * 256 + col;
            qpre[go] = f2bf(accq[n][j]);
            const int head = col >> 5, dm = col & 31;
            KT[head * 1024 + dm * 32 + rl] = f2bf(elu1(acck[n][j]));
            VT[head * 1024 + dm * 32 + rl] = f2bf(elu1(accv[n][j] + bv[col]));
        }
    __syncthreads();

    // ---- kv partial via MFMA: wave w = head w ----
    const ushort* vtw = VT + w * 1024;
    const ushort* ktw = KT + w * 1024;
    bf16x8 av[2], bk2[2];
#pragma unroll
    for (int i = 0; i < 2; ++i) {
        av[i]  = *(const bf16x8*)(vtw + (i * 16 + (lane & 15)) * 32 + (lane >> 4) * 8);
        bk2[i] = *(const bf16x8*)(ktw + (i * 16 + (lane & 15)) * 32 + (lane >> 4) * 8);
    }
    bf16x8 ones;
#pragma unroll
    for (int i = 0; i < 8; ++i) ones[i] = (__bf16)1.0f;
    f32x4 kvacc[2][2] = {};
    f32x4 ks[2] = {};
#pragma unroll
    for (int mi = 0; mi < 2; ++mi)
#pragma unroll
        for (int di = 0; di < 2; ++di)
            kvacc[mi][di] = MFMA16(av[mi], bk2[di], kvacc[mi][di]);
#pragma unroll
    for (int di = 0; di < 2; ++di) ks[di] = MFMA16(ones, bk2[di], ks[di]);

    float* pp = part + (size_t)qidx * 8448 + w * 1056;
#pragma unroll
    for (int mi = 0; mi < 2; ++mi)
#pragma unroll
        for (int di = 0; di < 2; ++di)
#pragma unroll
            for (int j = 0; j < 4; ++j) {
                const int m = mi * 16 + (lane >> 4) * 4 + j;
                const int d = di * 16 + (lane & 15);
                pp[m * 32 + d] = kvacc[mi][di][j];
            }
    if ((lane >> 4) == 0) {
        pp[1024 + (lane & 15)] = ks[0][0];
        pp[1024 + 16 + (lane & 15)] = ks[1][0];
    }
}

// ---------------- reduce 128 chunk-partials per (b,h); kv -> bf16, ksum -> fp32 ------
__global__ __launch_bounds__(256) void k_kvred(const float* __restrict__ part,
                                               ushort* __restrict__ kvbf,
                                               float* __restrict__ ksum) {
    const int i = blockIdx.x * 256 + threadIdx.x;   // 0..33791 (132*256)
    if (i >= 32 * 1056) return;
    const int bh = i / 1056, r = i - bh * 1056;
    const int b = bh >> 3, h = bh & 7;
    float s = 0.f;
#pragma unroll 8
    for (int c = 0; c < 128; ++c)
        s += part[(size_t)(b * 128 + c) * 8448 + h * 1056 + r];
    if (r < 1024) kvbf[(size_t)bh * 1024 + r] = f2bf(s);
    else          ksum[(size_t)bh * 32 + (r - 1024)] = s;
}

// ================= K3: q-finalize + MFMA attn + out-GEMM =================
// 256 blocks x 512 thr. attn numerator via per-head MFMA (wave w = head w);
// denominator via one VALU dot per (tok, head) into LDS.
__global__ __launch_bounds__(512, 2) void k_fusedB(const ushort* __restrict__ qpre,
                                                   const float* __restrict__ bias_g,
                                                   const ushort* __restrict__ kvbf,
                                                   const float* __restrict__ ksum,
                                                   const ushort* __restrict__ wo,
                                                   const float* __restrict__ bo,
                                                   float* __restrict__ out) {
    __shared__ ushort qs[64 * 256];    // linear bf16 q tile (32 KB)
    __shared__ ushort at_s[64 * 256];  // swizzled bf16 attn tile (32 KB)
    __shared__ ushort Ws2[256 * 32];   // 16 KB wo slice, slot-swizzled
    __shared__ float den_s[64][8];     // 2 KB
    const int t = threadIdx.x;
    const int w = t >> 6, lane = t & 63;
    const int tokBase = blockIdx.x * 64;
    const int b = tokBase >> 12;

#pragma unroll
    for (int j = 0; j < 4; ++j) {
        const int chunk = j * 512 + t;
        GLOAD_LDS16(qpre + (size_t)tokBase * 256 + (size_t)chunk * 8,
                    (char*)qs + chunk * 16);
    }
    __syncthreads();

    // ---- q finalize in-place: qs[r][cc] = bf16(elu1(qs[r][cc] + bias[r])) ----
    {
        const int r = t >> 3;
        const float brow = bias_g[tokBase + r];
        const int cb = (t & 7) * 32;
#pragma unroll
        for (int i = 0; i < 4; ++i) {
            bf16x8 qv = *(bf16x8*)(qs + r * 256 + cb + i * 8);
#pragma unroll
            for (int j = 0; j < 8; ++j) qv[j] = (__bf16)elu1((float)qv[j] + brow);
            *(bf16x8*)(qs + r * 256 + cb + i * 8) = qv;
        }
    }
    __syncthreads();

    // ---- denominator: den_s[tok][h] = q[tok][h,:] . ksum[b,h,:] + eps ----
    {
        const int tok = t >> 3, h = t & 7;
        const float* ksp = ksum + (size_t)(b * H_ + h) * HD_;
        float den = 0.f;
#pragma unroll
        for (int i = 0; i < 4; ++i) {
            const bf16x8 qv = *(const bf16x8*)(qs + tok * 256 + h * HD_ + i * 8);
            const f32x4 k0 = *(const f32x4*)(ksp + i * 8);
            const f32x4 k1 = *(const f32x4*)(ksp + i * 8 + 4);
#pragma unroll
            for (int j = 0; j < 4; ++j) {
                den = fmaf((float)qv[j], k0[j], den);
                den = fmaf((float)qv[j + 4], k1[j], den);
            }
        }
        den_s[tok][h] = den + EPSF;
    }

    // ---- numerator via MFMA: wave w = head w; Q[64x32] x kv_h[32x32]^T ----
    bf16x8 af[4], bfk[2];
#pragma unroll
    for (int mi = 0; mi < 4; ++mi)
        af[mi] = *(const bf16x8*)(qs + (mi * 16 + (lane & 15)) * 256 + w * HD_ +
                                  (lane >> 4) * 8);
#pragma unroll
    for (int ni = 0; ni < 2; ++ni)
        bfk[ni] = *(const bf16x8*)(kvbf +
                                   ((size_t)(b * H_ + w) * HD_ + ni * 16 + (lane & 15)) * HD_ +
                                   (lane >> 4) * 8);
    f32x4 nacc[4][2] = {};
#pragma unroll
    for (int mi = 0; mi < 4; ++mi)
#pragma unroll
        for (int ni = 0; ni < 2; ++ni)
            nacc[mi][ni] = MFMA16(af[mi], bfk[ni], nacc[mi][ni]);

    __syncthreads();   // den_s visible to all waves

    // ---- divide + write swizzled at_s ----
#pragma unroll
    for (int mi = 0; mi < 4; ++mi)
#pragma unroll
        for (int ni = 0; ni < 2; ++ni)
#pragma unroll
            for (int j = 0; j < 4; ++j) {
                const int tok = mi * 16 + (lane >> 4) * 4 + j;
                const int c2 = w * HD_ + ni * 16 + (lane & 15);
                const float a = nacc[mi][ni][j] / den_s[tok][w];
                const int byte = (tok * 512 + c2 * 2) ^ ((tok & 7) << 4);
                *(ushort*)((char*)at_s + byte) = f2bf(a);
            }

    // ---- out GEMM: 8 waves (2x4), wave tile 32 rows x 64 cols; wo from LDS ----
    const int wr = w >> 2, wc = w & 3;
    const int q_ = lane >> 4;
    f32x4 acc[2][4] = {};
    for (int kt = 0; kt < 256; kt += 32) {
        __syncthreads();   // first iteration also covers at_s writes
#pragma unroll
        for (int j = 0; j < 2; ++j) {
            const int ch = j * 512 + t;           // 0..1023
            const int e = ch >> 2;
            const int pslot = ch & 3;
            const int qsrc = pslot ^ ((e >> 1) & 3);
            GLOAD_LDS16(wo + (size_t)e * 256 + kt + qsrc * 8, (char*)Ws2 + ch * 16);
        }
        __syncthreads();
        bf16x8 af2[2];
#pragma unroll
        for (int mm = 0; mm < 2; ++mm) {
            const int r = wr * 32 + mm * 16 + (lane & 15);
            const int byte = (r * 512 + (kt + q_ * 8) * 2) ^ ((r & 7) << 4);
            af2[mm] = *(const bf16x8*)((const char*)at_s + byte);
        }
#pragma unroll
        for (int n = 0; n < 4; ++n) {
            const int e = wc * 64 + n * 16 + (lane & 15);
            const int wbyte = e * 64 + ((q_ ^ ((e >> 1) & 3)) * 16);
            const bf16x8 bw = *(const bf16x8*)((const char*)Ws2 + wbyte);
#pragma unroll
            for (int mm = 0; mm < 2; ++mm)
                acc[mm][n] = MFMA16(af2[mm], bw, acc[mm][n]);
        }
    }
#pragma unroll
    for (int mm = 0; mm < 2; ++mm)
#pragma unroll
        for (int n = 0; n < 4; ++n)
#pragma unroll
            for (int j = 0; j < 4; ++j) {
                const int row = tokBase + wr * 32 + mm * 16 + (lane >> 4) * 4 + j;
                const int col = wc * 64 + n * 16 + (lane & 15);
                out[(size_t)row * 256 + col] = acc[mm][n][j] + bo[col];
            }
}

extern "C" void kernel_launch(void* const* d_in, const int* in_sizes, int n_in,
                              void* d_out, int out_size, void* d_ws, size_t ws_size,
                              hipStream_t stream) {
    const float* x     = (const float*)d_in[0];
    const float* prior = (const float*)d_in[1];
    const float* Wq    = (const float*)d_in[2];
    const float* Wk    = (const float*)d_in[3];
    const float* Wv    = (const float*)d_in[4];
    const float* bv    = (const float*)d_in[5];
    const float* Wo    = (const float*)d_in[6];
    const float* bo    = (const float*)d_in[7];
    float* out = (float*)d_out;

    // workspace layout
    char* w8 = (char*)d_ws;
    ushort* qpre = (ushort*)w8;                         // 8 MB bf16
    ushort* wqb  = qpre + (size_t)TOKENS * D_;          // 4 x 128 KB bf16
    ushort* wkb  = wqb + 65536;
    ushort* wvb  = wkb + 65536;
    ushort* wob  = wvb + 65536;
    ushort* kvbf = wob + 65536;                         // 64 KB bf16 kv summary
    float* ksb   = (float*)(kvbf + 32768);              // 4 KB
    float* bias  = ksb + 1024;                          // 64 KB
    float* part  = bias + TOKENS;                       // 512*8448*4 = 17.3 MB

    k_cvt_w<<<128, 256, 0, stream>>>(Wq, Wk, Wv, Wo, wqb);

    k_mix2<<<2560, 512, 0, stream>>>(prior, x, wqb, wkb, wvb, bv, bias, qpre, part);

    k_kvred<<<132, 256, 0, stream>>>(part, kvbf, ksb);

    k_fusedB<<<256, 512, 0, stream>>>(qpre, bias, kvbf, ksb, wob, bo, out);
}